// Round 9
// baseline (2352.553 us; speedup 1.0000x reference)
//
#include <hip/hip_runtime.h>
#include <hip/hip_bf16.h>

// LSTM B=1024 T=256 IN=64 H=512. Round 14: dual-chain software pipelining.
// R10/R13 proved TLP (more blocks or waves) cannot hide the exchange: all
// waves wait on the SAME global step cadence simultaneously. The only
// independent work is another batch slice. Restructure: 64 m-groups of 16
// rows; each block owns TWO tasks (group p, jb) and (group p+32, jb) --
// same jb => SAME weights (bfr shared). Iteration = phase A then phase B;
// phase A's exchange (store ack, flag propagation, remote reads) overlaps
// phase B's compute: each exchange gets ~half an iteration of propagation
// slack, so polls pass on first sample and only one h-load rtt is exposed
// per phase (vs ~3.6us serial exchange in R9).
// Cost: 16-row A-tile in 32x32 MFMA wastes rows 16..31 (C regs 8..15
// garbage, epilogue uses regs 0..7 only) -> MFMA issue 2x (+0.25us/iter,
// cheap at 15% util). Per-step LDS bytes, h/x HBM traffic, epilogue VALU,
// and register footprint are IDENTICAL to R9 (bfr/acc shared across tasks;
// cr[2][2][8] = R9's 32 regs). 4 anonymous barriers/iter keep the 4 waves
// phase-lockstepped (prevents mismatched-barrier races between phases).
// Flags: 64 groups x 32 per-wave slots (8 jb x 4 w) = 8KB, memset 0.
// Protocol per phase unchanged from R9: poll (lanes watch one flag each,
// watchdog 2^14) -> agent h-loads -> stage -> barrier -> MFMA -> DPP
// epilogue -> agent h-stores -> vmcnt drain -> publish own flag -> barrier.
// 3-buffer h rotation: per-group skew<=1 argument unchanged.

#define TST   256
#define BATCH 1024
#define HID   512
#define INSZ  64
#define NCLS  10
#define LDSTR 584   // elem stride: 1168 B = 292 dw = 4 mod 32 -> conflict-free

typedef _Float16 f16x8  __attribute__((ext_vector_type(8)));
typedef float    f32x16 __attribute__((ext_vector_type(16)));
typedef unsigned long long u64;

__device__ __forceinline__ float fast_rcp(float x) {
    return __builtin_amdgcn_rcpf(x);   // v_rcp_f32, ~1 ulp
}

__device__ __forceinline__ float tanh_f(float x) {
    return 2.0f * fast_rcp(1.0f + __expf(-2.0f * x)) - 1.0f;
}

__device__ __forceinline__ f16x8 cvt8(float4 a, float4 b) {
    f16x8 o;
    o[0] = (_Float16)a.x; o[1] = (_Float16)a.y; o[2] = (_Float16)a.z; o[3] = (_Float16)a.w;
    o[4] = (_Float16)b.x; o[5] = (_Float16)b.y; o[6] = (_Float16)b.z; o[7] = (_Float16)b.w;
    return o;
}

__device__ __forceinline__ u64 cvt4_u64(float4 a) {
    _Float16 h[4] = {(_Float16)a.x, (_Float16)a.y, (_Float16)a.z, (_Float16)a.w};
    u64 r;
    __builtin_memcpy(&r, h, 8);
    return r;
}

template <int CTRL>
__device__ __forceinline__ float dpp_f(float v) {
    return __builtin_bit_cast(float,
        __builtin_amdgcn_mov_dpp(__builtin_bit_cast(int, v), CTRL, 0xF, 0xF, true));
}
template <int CTRL>
__device__ __forceinline__ unsigned dpp_u(unsigned v) {
    return (unsigned)__builtin_amdgcn_mov_dpp((int)v, CTRL, 0xF, 0xF, true);
}
// DPP ctrls: quad_perm xor1=0xB1, xor2=0x4E, xor3=0x1B (symmetric);
// row_shl:4=0x104, row_shl:8=0x108 (dst lane i <- src lane i+N).

__global__ __launch_bounds__(256, 1) void lstm_persist(
    const float* __restrict__ x,   const float* __restrict__ h0,
    const float* __restrict__ c0,  const float* __restrict__ Wih,
    const float* __restrict__ Whh, const float* __restrict__ bih,
    const float* __restrict__ bhh, _Float16* __restrict__ hb,
    unsigned* __restrict__ bar)
{
    // Two 32-row tiles; only rows 0..15 of each are staged (16-row tasks).
    // MFMA A-reads touch rows 0..31: 16..31 are in-bounds garbage whose
    // products land in C regs 8..15, which the epilogue never reads.
    __shared__ __align__(16) _Float16 As[2][32][LDSTR];   // 74752 B

    const int tid   = threadIdx.x;
    const int lane  = tid & 63;
    const int w     = tid >> 6;        // wave 0..3
    const int l31   = lane & 31;
    const int khalf = (lane >> 5) * 8;
    const int p  = (int)(blockIdx.x >> 3);   // group-pair 0..31
    const int jb = (int)(blockIdx.x & 7);    // j-block 0..7
    const int j0 = jb * 64;
    const int m0T[2]      = { p * 16, 512 + p * 16 };   // 16 batch rows each
    unsigned* const flgT[2] = { bar + p * 32, bar + (32 + p) * 32 };

    const int gate = l31 & 3;                // nt*32 preserves np&3
    int jcol[2], nrow[2];
    #pragma unroll
    for (int nt = 0; nt < 2; ++nt) {
        int np = w * 64 + nt * 32 + l31;
        jcol[nt] = j0 + (np >> 2);
        nrow[nt] = gate * HID + jcol[nt];
    }

    // ---- B fragments in registers (one-time, SHARED by both tasks) ----
    f16x8 bfr[2][36];
    #pragma unroll
    for (int nt = 0; nt < 2; ++nt)
        #pragma unroll
        for (int kt = 0; kt < 36; ++kt) {
            const int k0 = kt * 16 + khalf;
            const float* ptr = (kt < 32) ? (Whh + (size_t)nrow[nt] * HID + k0)
                                         : (Wih + (size_t)nrow[nt] * INSZ + (k0 - HID));
            float4 f0 = ((const float4*)ptr)[0];
            float4 f1 = ((const float4*)ptr)[1];
            bfr[nt][kt] = cvt8(f0, f1);
        }
    float bsv[2];
    bsv[0] = bih[nrow[0]] + bhh[nrow[0]];
    bsv[1] = bih[nrow[1]] + bhh[nrow[1]];
    const float s   = (gate == 2) ? 2.0f : 1.0f;   // tanh for g, sigmoid otherwise
    const int rowhi = (lane >> 5) * 4;

    // ---- c state: [task][nt][reg 0..7] -> rows 0..15 of each task ----
    float cr[2][2][8];
    #pragma unroll
    for (int task = 0; task < 2; ++task)
        #pragma unroll
        for (int nt = 0; nt < 2; ++nt)
            #pragma unroll
            for (int r = 0; r < 8; ++r) {
                int row = (r & 3) + 8 * (r >> 2) + rowhi;   // 0..15
                cr[task][nt][r] = c0[(size_t)(m0T[task] + row) * HID + jcol[nt]];
            }

    const int rr = tid >> 4;       // staging: 16 threads per row (16 rows)
    const int q  = tid & 15;

    for (int t = 0; t < TST; ++t) {
        const _Float16* rb = hb + (size_t)((t + 2) % 3) * (BATCH * HID);
        _Float16*       wb = hb + (size_t)(t % 3) * (BATCH * HID);

        #pragma unroll
        for (int task = 0; task < 2; ++task) {
            unsigned* flg = flgT[task];
            const int mb  = m0T[task];

            // x load first: latency hides under the flag poll
            float4 x0 = *(const float4*)(x + (size_t)(mb + rr) * (TST * INSZ)
                                           + t * INSZ + q * 4);

            if (t == 0) {
                u64 hv[8];
                #pragma unroll
                for (int u = 0; u < 8; ++u) {
                    float4 f = *(const float4*)(h0 + (size_t)(mb + rr) * HID
                                                  + q * 4 + u * 64);
                    hv[u] = cvt4_u64(f);
                }
                #pragma unroll
                for (int u = 0; u < 8; ++u)
                    *(u64*)&As[task][rr][q * 4 + u * 64] = hv[u];
            } else {
                // poll: lanes watch flag (lane&31); producers published t
                // during the OTHER phase of the previous iteration, so this
                // normally passes on the first sample. Watchdog: 2^14 spins
                // -> a sync bug becomes a wrong answer, never a hang.
                const unsigned tgt = (unsigned)t;
                int spins = 0;
                while (true) {
                    unsigned v = __hip_atomic_load(flg + (lane & 31),
                                                   __ATOMIC_RELAXED,
                                                   __HIP_MEMORY_SCOPE_AGENT);
                    if (__all((int)(v >= tgt))) break;
                    if (++spins > (1 << 14)) break;   // watchdog
                    __builtin_amdgcn_s_sleep(1);
                }
                __atomic_signal_fence(__ATOMIC_SEQ_CST);
                const u64* rbq = (const u64*)(rb + (size_t)(mb + rr) * HID);
                u64 hv[8];
                #pragma unroll
                for (int u = 0; u < 8; ++u)
                    hv[u] = __hip_atomic_load(&rbq[q + u * 16],
                                              __ATOMIC_RELAXED,
                                              __HIP_MEMORY_SCOPE_AGENT);
                #pragma unroll
                for (int u = 0; u < 8; ++u)
                    *(u64*)&As[task][rr][q * 4 + u * 64] = hv[u];
            }
            *(u64*)&As[task][rr][512 + q * 4] = cvt4_u64(x0);  // x_t k 512..575
            __syncthreads();   // staging join

            // ---- MFMA: 36 k-tiles, 1 A-read feeds both n-tiles ----
            f32x16 acc[2];
            #pragma unroll
            for (int i = 0; i < 16; ++i) { acc[0][i] = 0.0f; acc[1][i] = 0.0f; }
            #pragma unroll
            for (int kt = 0; kt < 36; ++kt) {
                f16x8 af = *(const f16x8*)&As[task][l31][kt * 16 + khalf];
                acc[0] = __builtin_amdgcn_mfma_f32_32x32x16_f16(af, bfr[0][kt], acc[0], 0, 0, 0);
                acc[1] = __builtin_amdgcn_mfma_f32_32x32x16_f16(af, bfr[1][kt], acc[1], 0, 0, 0);
            }

            // ---- epilogue: regs 0..7 only (rows 0..15); DPP gate combine ----
            #pragma unroll
            for (int nt = 0; nt < 2; ++nt) {
                #pragma unroll
                for (int r = 0; r < 8; ++r) {
                    float v = acc[nt][r] + bsv[nt];
                    float e = __expf(-s * v);
                    float act = s * fast_rcp(1.0f + e) - (s - 1.0f);
                    float fu = dpp_f<0xB1>(act);   // quad xor1: f
                    float gu = dpp_f<0x4E>(act);   // quad xor2: g
                    float ou = dpp_f<0x1B>(act);   // quad xor3: o
                    float cn = fu * cr[task][nt][r] + act * gu;
                    cr[task][nt][r] = cn;
                    float hn = ou * tanh_f(cn);
                    unsigned hu = (unsigned)__builtin_bit_cast(unsigned short, (_Float16)hn);
                    unsigned pk = hu | (dpp_u<0x104>(hu) << 16);          // <- lane+4
                    u64 v4 = (u64)pk | ((u64)dpp_u<0x108>(pk) << 32);     // <- lane+8
                    if ((l31 & 15) == 0) {
                        int row = (r & 3) + 8 * (r >> 2) + rowhi;        // 0..15
                        __hip_atomic_store(
                            (u64*)&wb[(size_t)(mb + row) * HID + jcol[nt]],
                            v4, __ATOMIC_RELAXED, __HIP_MEMORY_SCOPE_AGENT);
                    }
                }
            }

            // ---- per-wave release: drain own stores, publish own flag ----
            asm volatile("s_waitcnt vmcnt(0)" ::: "memory");
            if (lane == 0)
                __hip_atomic_store(flg + (jb * 4 + w), (unsigned)(t + 1),
                                   __ATOMIC_RELAXED, __HIP_MEMORY_SCOPE_AGENT);
            __syncthreads();   // phase end: keep waves phase-lockstepped
        }
    }
}

// ---------------- final linear: preds = hT @ W_lin^T + b_lin ----------------
__global__ __launch_bounds__(256) void final_kernel(
    const _Float16* __restrict__ h, const float* __restrict__ Wl,
    const float* __restrict__ bl, float* __restrict__ out)
{
    int i = blockIdx.x * 256 + threadIdx.x;
    if (i >= BATCH * NCLS) return;
    int b = i / NCLS, c = i - b * NCLS;
    const f16x8* hp = (const f16x8*)(h + (size_t)b * HID);
    const float4* wp = (const float4*)(Wl + (size_t)c * HID);
    float sacc = bl[c];
    #pragma unroll 4
    for (int k8 = 0; k8 < HID / 8; ++k8) {
        f16x8 hv = hp[k8];
        float4 w0 = wp[2 * k8], w1 = wp[2 * k8 + 1];
        sacc += (float)hv[0] * w0.x + (float)hv[1] * w0.y +
                (float)hv[2] * w0.z + (float)hv[3] * w0.w +
                (float)hv[4] * w1.x + (float)hv[5] * w1.y +
                (float)hv[6] * w1.z + (float)hv[7] * w1.w;
    }
    out[i] = sacc;
}

extern "C" void kernel_launch(void* const* d_in, const int* in_sizes, int n_in,
                              void* d_out, int out_size, void* d_ws, size_t ws_size,
                              hipStream_t stream)
{
    const float* x    = (const float*)d_in[0];
    const float* h0   = (const float*)d_in[1];
    const float* c0   = (const float*)d_in[2];
    const float* Wih  = (const float*)d_in[3];
    const float* Whh  = (const float*)d_in[4];
    const float* bih  = (const float*)d_in[5];
    const float* bhh  = (const float*)d_in[6];
    const float* Wlin = (const float*)d_in[7];
    const float* blin = (const float*)d_in[8];
    float* out = (float*)d_out;

    unsigned* bar = (unsigned*)d_ws;                   // 64 groups x 32 wave-flags
    _Float16* hb  = (_Float16*)((char*)d_ws + 8192);   // 3 x 1 MB h buffers

    hipMemsetAsync(d_ws, 0, 8192, stream);             // zero release flags

    // 256 blocks, 1/CU: each block pipelines two independent 16-row chains
    // (groups p and p+32, same jb => shared weights).
    lstm_persist<<<256, 256, 0, stream>>>(x, h0, c0, Wih, Whh, bih, bhh, hb, bar);

    // step t=255 wrote buffer (255 % 3) == 0 -> hb
    final_kernel<<<(BATCH * NCLS + 255) / 256, 256, 0, stream>>>(hb, Wlin, blin, out);
}

// Round 10
// 1750.467 us; speedup vs baseline: 1.3440x; 1.3440x over previous
//
#include <hip/hip_runtime.h>
#include <hip/hip_bf16.h>

// LSTM B=1024 T=256 IN=64 H=512. Round 15: self-certifying tagged exchange.
// R9's 6.8us step contains THREE serialized exchange round-trips: producer
// store-ack drain (vmcnt0, ~1 rtt) -> flag publish+propagate -> consumer
// h-load (~1 rtt). R14 proved phase-pipelining can't hide them (each phase
// embeds its own). This round merges all three into ONE: h is published as
// 8B units {2 x f16, u32 step-tag}.
//   producer: fire-and-forget tagged stores. NO drain, NO flag (release
//             section deleted). Same-address store-store ordering across
//             the 3-slot rotation is enforced by the next steps' load
//             waitcnts (vmcnt is joint in-order for loads+stores).
//   consumer: the h-load IS the poll: load its row's 32 tagged u64s,
//             check all tags == t, retry on mismatch (watchdog 2^14).
//             Data visible <=> tag visible (8B single-store atomicity).
//   LDS-reuse token survives: a VISIBLE h_t store by wave W implies W
//             finished ALL its As reads (hn <- acc <- all 36 ds_reads),
//             so tag-pass licenses overwriting As; the single post-staging
//             __syncthreads stays the only barrier.
//   stale-tag safety: equality check + 6MB memset per launch (tags start
//             0); rotation overwrite can't outrun readers (3-buffer
//             argument unchanged); any violation -> watchdog -> visible
//             wrong answer, never a hang.
// Costs: h buffer 1->2MB/slot, h bytes 2x, +tag-check VALU, +64 VGPR load
// staging (harmless: 1 block/CU => up to 512 regs/wave).
// Everything else is R9: 32 m-groups x 8 j-blocks, 256 blocks (1/CU),
// register-resident f16 weights, 1 A-read feeds 2 MFMAs, DPP epilogue
// (quad gate combine + row_shl pack), fast rcp.

#define TST   256
#define BATCH 1024
#define HID   512
#define INSZ  64
#define NCLS  10
#define LDSTR 584   // elem stride: 1168 B = 292 dw = 4 mod 32 -> conflict-free

typedef _Float16 f16x8  __attribute__((ext_vector_type(8)));
typedef float    f32x16 __attribute__((ext_vector_type(16)));
typedef unsigned long long u64;

__device__ __forceinline__ float fast_rcp(float x) {
    return __builtin_amdgcn_rcpf(x);   // v_rcp_f32, ~1 ulp
}

__device__ __forceinline__ float tanh_f(float x) {
    return 2.0f * fast_rcp(1.0f + __expf(-2.0f * x)) - 1.0f;
}

__device__ __forceinline__ f16x8 cvt8(float4 a, float4 b) {
    f16x8 o;
    o[0] = (_Float16)a.x; o[1] = (_Float16)a.y; o[2] = (_Float16)a.z; o[3] = (_Float16)a.w;
    o[4] = (_Float16)b.x; o[5] = (_Float16)b.y; o[6] = (_Float16)b.z; o[7] = (_Float16)b.w;
    return o;
}

template <int CTRL>
__device__ __forceinline__ float dpp_f(float v) {
    return __builtin_bit_cast(float,
        __builtin_amdgcn_mov_dpp(__builtin_bit_cast(int, v), CTRL, 0xF, 0xF, true));
}
template <int CTRL>
__device__ __forceinline__ unsigned dpp_u(unsigned v) {
    return (unsigned)__builtin_amdgcn_mov_dpp((int)v, CTRL, 0xF, 0xF, true);
}
// DPP ctrls: quad_perm xor1=0xB1, xor2=0x4E, xor3=0x1B (symmetric);
// row_shl:4=0x104 (dst lane i <- src lane i+4).

__global__ __launch_bounds__(256, 1) void lstm_persist(
    const float* __restrict__ x,   const float* __restrict__ h0,
    const float* __restrict__ c0,  const float* __restrict__ Wih,
    const float* __restrict__ Whh, const float* __restrict__ bih,
    const float* __restrict__ bhh, u64* __restrict__ hb)
{
    __shared__ __align__(16) _Float16 As[32][LDSTR];   // 37376 B

    const int tid   = threadIdx.x;
    const int lane  = tid & 63;
    const int w     = tid >> 6;        // wave 0..3
    const int l31   = lane & 31;
    const int khalf = (lane >> 5) * 8;
    const int g  = (int)(blockIdx.x >> 3);   // m-group 0..31
    const int jb = (int)(blockIdx.x & 7);    // j-block 0..7
    const int m0 = g * 32;
    const int j0 = jb * 64;

    const int gate = l31 & 3;                // nt*32 preserves np&3
    int jcol[2], nrow[2];
    #pragma unroll
    for (int nt = 0; nt < 2; ++nt) {
        int np = w * 64 + nt * 32 + l31;
        jcol[nt] = j0 + (np >> 2);
        nrow[nt] = gate * HID + jcol[nt];
    }

    // ---- B fragments in registers (one-time): bfr[nt][kt] ----
    f16x8 bfr[2][36];
    #pragma unroll
    for (int nt = 0; nt < 2; ++nt)
        #pragma unroll
        for (int kt = 0; kt < 36; ++kt) {
            const int k0 = kt * 16 + khalf;
            const float* p = (kt < 32) ? (Whh + (size_t)nrow[nt] * HID + k0)
                                       : (Wih + (size_t)nrow[nt] * INSZ + (k0 - HID));
            float4 f0 = ((const float4*)p)[0];
            float4 f1 = ((const float4*)p)[1];
            bfr[nt][kt] = cvt8(f0, f1);
        }
    float bsv[2];
    bsv[0] = bih[nrow[0]] + bhh[nrow[0]];
    bsv[1] = bih[nrow[1]] + bhh[nrow[1]];
    const float s   = (gate == 2) ? 2.0f : 1.0f;   // tanh for g, sigmoid otherwise
    const int rowhi = (lane >> 5) * 4;

    // ---- c state in registers (lead lanes l31%4==0 hold the real values) ----
    float cr[2][16];
    #pragma unroll
    for (int nt = 0; nt < 2; ++nt)
        #pragma unroll
        for (int r = 0; r < 16; ++r) {
            int row = (r & 3) + 8 * (r >> 2) + rowhi;
            cr[nt][r] = c0[(size_t)(m0 + row) * HID + jcol[nt]];
        }

    const int rr = tid >> 3;       // staging: 8 threads per row (32 rows)
    const int q  = tid & 7;

    for (int t = 0; t < TST; ++t) {
        // tagged u64 units: 256 per batch row (2 f16 + tag each)
        const u64* rb = hb + (size_t)((t + 2) % 3) * (BATCH * HID / 2);
        u64*       wb = hb + (size_t)(t % 3) * (BATCH * HID / 2);

        // ---- issue x loads first: their latency hides under the data poll ----
        float4 x0, x1;
        {
            const float* xp = x + (size_t)(m0 + rr) * (TST * INSZ) + t * INSZ + q * 8;
            x0 = ((const float4*)xp)[0];
            x1 = ((const float4*)xp)[1];
        }
        if (t == 0) {
            #pragma unroll
            for (int u = 0; u < 16; ++u) {
                float4 f = *(const float4*)(h0 + (size_t)(m0 + rr) * HID + q * 4 + u * 32);
                _Float16 h4[4] = {(_Float16)f.x, (_Float16)f.y, (_Float16)f.z, (_Float16)f.w};
                u64 r8; __builtin_memcpy(&r8, h4, 8);
                *(u64*)&As[rr][q * 4 + u * 32] = r8;
            }
        } else {
            // ---- tagged-data poll: load own row's 32 u64s, all tags must
            // equal t (producers wrote tag u+1 at step u). Retry until they
            // do; watchdog 2^14 -> wrong answer, never a wedged container.
            const unsigned tgt = (unsigned)t;
            const u64* rbq = rb + (size_t)(m0 + rr) * 256;
            u64 hv[32];
            int spins = 0;
            while (true) {
                unsigned bad = 0;
                #pragma unroll
                for (int u = 0; u < 32; ++u)
                    hv[u] = __hip_atomic_load(&rbq[q + u * 8],
                                              __ATOMIC_RELAXED, __HIP_MEMORY_SCOPE_AGENT);
                #pragma unroll
                for (int u = 0; u < 32; ++u)
                    bad |= ((unsigned)(hv[u] >> 32)) ^ tgt;
                if (__all((int)(bad == 0))) break;
                if (++spins > (1 << 14)) break;   // watchdog (never in practice)
                __builtin_amdgcn_s_sleep(8);
            }
            __atomic_signal_fence(__ATOMIC_SEQ_CST);
            #pragma unroll
            for (int u = 0; u < 32; ++u)
                *(unsigned*)&As[rr][(q + u * 8) * 2] = (unsigned)hv[u];
        }
        *(f16x8*)&As[rr][512 + q * 8] = cvt8(x0, x1);   // x_t -> k 512..575
        __syncthreads();   // staging join (the only barrier per step)

        // ---- MFMA: 36 k-tiles, 1 A-read feeds both n-tiles ----
        f32x16 acc[2];
        #pragma unroll
        for (int i = 0; i < 16; ++i) { acc[0][i] = 0.0f; acc[1][i] = 0.0f; }
        #pragma unroll
        for (int kt = 0; kt < 36; ++kt) {
            f16x8 af = *(const f16x8*)&As[l31][kt * 16 + khalf];
            acc[0] = __builtin_amdgcn_mfma_f32_32x32x16_f16(af, bfr[0][kt], acc[0], 0, 0, 0);
            acc[1] = __builtin_amdgcn_mfma_f32_32x32x16_f16(af, bfr[1][kt], acc[1], 0, 0, 0);
        }

        // ---- epilogue: DPP gate combine, c/h update, tagged 8B stores
        // (fire-and-forget: no drain, no flag -- the tag IS the release) ----
        const u64 tag64 = ((u64)(unsigned)(t + 1)) << 32;
        #pragma unroll
        for (int nt = 0; nt < 2; ++nt) {
            #pragma unroll
            for (int r = 0; r < 16; ++r) {
                float v = acc[nt][r] + bsv[nt];
                float e = __expf(-s * v);
                float act = s * fast_rcp(1.0f + e) - (s - 1.0f);   // sigmoid or tanh
                float fu = dpp_f<0xB1>(act);   // quad xor1: f
                float gu = dpp_f<0x4E>(act);   // quad xor2: g
                float ou = dpp_f<0x1B>(act);   // quad xor3: o
                float cn = fu * cr[nt][r] + act * gu;
                cr[nt][r] = cn;
                float hn = ou * tanh_f(cn);
                unsigned hu = (unsigned)__builtin_bit_cast(unsigned short, (_Float16)hn);
                unsigned pk = hu | (dpp_u<0x104>(hu) << 16);   // {h(c), h(c+1)}
                if ((l31 & 7) == 0) {
                    int row = (r & 3) + 8 * (r >> 2) + rowhi;
                    __hip_atomic_store(
                        wb + ((size_t)(m0 + row) * HID + jcol[nt]) / 2,
                        (u64)pk | tag64,
                        __ATOMIC_RELAXED, __HIP_MEMORY_SCOPE_AGENT);
                }
            }
        }
        // no release section: loop directly into the next step.
    }
}

// ---------------- final linear: preds = hT @ W_lin^T + b_lin ----------------
__global__ __launch_bounds__(256) void final_kernel(
    const u64* __restrict__ h, const float* __restrict__ Wl,
    const float* __restrict__ bl, float* __restrict__ out)
{
    int i = blockIdx.x * 256 + threadIdx.x;
    if (i >= BATCH * NCLS) return;
    int b = i / NCLS, c = i - b * NCLS;
    const u64* hp = h + (size_t)b * (HID / 2);
    const float2* wp = (const float2*)(Wl + (size_t)c * HID);
    float sacc = bl[c];
    #pragma unroll 8
    for (int k2 = 0; k2 < HID / 2; ++k2) {
        unsigned lo = (unsigned)hp[k2];
        _Float16 h0v = __builtin_bit_cast(_Float16, (unsigned short)(lo & 0xFFFF));
        _Float16 h1v = __builtin_bit_cast(_Float16, (unsigned short)(lo >> 16));
        float2 wv = wp[k2];
        sacc += (float)h0v * wv.x + (float)h1v * wv.y;
    }
    out[i] = sacc;
}

extern "C" void kernel_launch(void* const* d_in, const int* in_sizes, int n_in,
                              void* d_out, int out_size, void* d_ws, size_t ws_size,
                              hipStream_t stream)
{
    const float* x    = (const float*)d_in[0];
    const float* h0   = (const float*)d_in[1];
    const float* c0   = (const float*)d_in[2];
    const float* Wih  = (const float*)d_in[3];
    const float* Whh  = (const float*)d_in[4];
    const float* bih  = (const float*)d_in[5];
    const float* bhh  = (const float*)d_in[6];
    const float* Wlin = (const float*)d_in[7];
    const float* blin = (const float*)d_in[8];
    float* out = (float*)d_out;

    u64* hb = (u64*)d_ws;   // 3 slots x 2MB tagged h buffers

    // zero ALL tags each launch: fresh run starts with tag 0 < expected,
    // so the equality poll can never pass on a previous run's residue.
    hipMemsetAsync(d_ws, 0, 3 * (size_t)(BATCH * HID / 2) * 8, stream);

    // 256 blocks, 1/CU (launch_bounds(256,1), 37KB LDS) -> all co-resident.
    lstm_persist<<<256, 256, 0, stream>>>(x, h0, c0, Wih, Whh, bih, bhh, hb);

    // step t=255 wrote slot (255 % 3) == 0 -> hb
    final_kernel<<<(BATCH * NCLS + 255) / 256, 256, 0, stream>>>(hb, Wlin, blin, out);
}